// Round 3
// baseline (179.198 us; speedup 1.0000x reference)
//
#include <hip/hip_runtime.h>
#include <hip/hip_bf16.h>

#define BATCH 16
#define CIN   128
#define HIMG  56
#define WIMG  56
#define NPIX  (HIMG*WIMG)      // 3136
#define CS    256
#define NQ    4
#define HOUT  28
#define WOUT  28
#define NOPIX (HOUT*WOUT)      // 784
#define QSCALE 0.17677669529663687f   // hc^-0.5 = 1/sqrt(32)
#define NCOL  288              // 256 V cols + 32 qk cols

typedef __attribute__((ext_vector_type(8))) short  bf16x8;
typedef __attribute__((ext_vector_type(4))) float  f32x4;

static __device__ __forceinline__ unsigned short f2bf(float f) {
    return __builtin_bit_cast(unsigned short, __float2bfloat16(f));
}
static __device__ __forceinline__ unsigned int pack2(float a, float b) {
    return (unsigned)f2bf(a) | ((unsigned)f2bf(b) << 16);
}

// ---------- kernel 0: transpose Wout (o,c) -> WoutT (c,o) ----------
__global__ __launch_bounds__(256) void k0_transpose(const float* __restrict__ Wout,
                                                    float* __restrict__ WoutT) {
    const int c = blockIdx.x, o = threadIdx.x;
    WoutT[c*CS + o] = Wout[o*CS + c];
}

// ---------- kernel 0b: build W' = [WvT | Wq'] bf16, XOR-swizzled rows ----------
// Row n (= GEMM column n) occupies 256 bytes; byte k-offset is XORed with
// ((n&7)<<4) so k1's B-frag ds_read_b128 is bank-conflict-free (T2).
__global__ __launch_bounds__(256) void k0b_foldw(
    const float* __restrict__ Wk, const float* __restrict__ Wv,
    const float* __restrict__ qp, unsigned short* __restrict__ Wp)
{
    __shared__ float qs[NQ*CS];
    const int t = threadIdx.x;
    for (int i = t; i < NQ*CS; i += 256) qs[i] = qp[i] * QSCALE;
    __syncthreads();

    char* wp = (char*)Wp;
    {   // WvT rows 0..255: row ch holds Wv[*, ch]
        const int ch = t;
        const int mask = (ch & 7) << 4;
        for (int c2 = 0; c2 < 64; ++c2) {
            const float f0 = Wv[(2*c2+0)*CS + ch];
            const float f1 = Wv[(2*c2+1)*CS + ch];
            *(unsigned*)(wp + ch*256 + ((c2*4) ^ mask)) = pack2(f0, f1);
        }
    }
    if (t < 32) {  // Wq' rows 256..287: row 256+qh, qh = q*8+h
        const int qh = t, h = qh & 7, q = qh >> 3;
        const int row = 256 + qh;
        const int mask = (row & 7) << 4;   // == (qh&7)<<4
        const float* qv = &qs[q*CS + h*32];
        for (int c2 = 0; c2 < 64; ++c2) {
            float d0 = 0.f, d1 = 0.f;
            const float* wk0 = Wk + (size_t)(2*c2+0)*CS + h*32;
            const float* wk1 = Wk + (size_t)(2*c2+1)*CS + h*32;
            #pragma unroll
            for (int j = 0; j < 32; ++j) {
                d0 = fmaf(wk0[j], qv[j], d0);
                d1 = fmaf(wk1[j], qv[j], d1);
            }
            *(unsigned*)(wp + row*256 + ((c2*4) ^ mask)) = pack2(d0, d1);
        }
    }
}

// ---------- kernel T: x (B,C,N) f32 -> xT (B*N, 128) bf16 (row-major, linear) ----------
__global__ __launch_bounds__(256) void kT_transpose(
    const float* __restrict__ x, unsigned short* __restrict__ xT)
{
    __shared__ float lt[CIN][66];   // +2 pad
    const int t   = threadIdx.x;
    const int blk = blockIdx.x;            // b*49 + ptile
    const int b   = blk / (NPIX/64);
    const int p0  = (blk % (NPIX/64)) * 64;

    {   // load 128c x 64p tile, coalesced float4
        const int c0 = t >> 4;             // 0..15
        const int f4 = t & 15;             // 16 float4 per row
        #pragma unroll
        for (int i = 0; i < 8; ++i) {
            const int c = c0 + i*16;
            const float4 v = *(const float4*)(x + ((size_t)b*CIN + c)*NPIX + p0 + f4*4);
            lt[c][f4*4+0] = v.x; lt[c][f4*4+1] = v.y;
            lt[c][f4*4+2] = v.z; lt[c][f4*4+3] = v.w;
        }
    }
    __syncthreads();

    // write: thread -> (pixel p = t>>2, c-segment seg = t&3 covering 32 c)
    const int p = t >> 2, seg = t & 3;
    unsigned short* orow = xT + ((size_t)(b*NPIX) + p0 + p)*CIN + seg*32;
    #pragma unroll
    for (int g = 0; g < 4; ++g) {          // 8 c per 16B store
        const int c0 = seg*32 + g*8;
        uint4 u;
        u.x = pack2(lt[c0+0][p], lt[c0+1][p]);
        u.y = pack2(lt[c0+2][p], lt[c0+3][p]);
        u.z = pack2(lt[c0+4][p], lt[c0+5][p]);
        u.w = pack2(lt[c0+6][p], lt[c0+7][p]);
        *(uint4*)(orow + g*8) = u;
    }
}

// ---------- kernel 1: MFMA GEMM xT(50176x128) @ W'(128x288) -> V + cost ----------
// Block = 64 pixels x 288 cols, 4 waves (wave w owns pixel rows w*16..w*16+15).
// A-frags straight from global (read once); B staged fully in LDS (73.7 KB,
// pre-swizzled by k0b so frag reads are conflict-free). Single K pass (4 ksteps).
__global__ __launch_bounds__(256, 2) void k1_mfma(
    const unsigned short* __restrict__ xT, const unsigned short* __restrict__ Wp,
    float* __restrict__ costO, float* __restrict__ Vout)
{
    __shared__ unsigned short Blds[NCOL*CIN];   // 73728 B

    const int t    = threadIdx.x;
    const int lane = t & 63;
    const int w    = t >> 6;
    const int l15  = lane & 15;
    const int hi   = lane >> 4;
    const int gp0  = blockIdx.x * 64;           // global (b*NPIX+p) row base

    // A-frags: wave w, row l15, kstep s -> k = s*32 + hi*8   (4 x 16B, HBM/L1)
    const unsigned short* arow = xT + ((size_t)(gp0 + w*16 + l15))*CIN + hi*8;
    bf16x8 afr[4];
    #pragma unroll
    for (int s = 0; s < 4; ++s)
        afr[s] = *(const bf16x8*)(arow + s*32);

    // stage B: linear copy of the pre-swizzled image (L2-resident after round 1)
    {
        const bf16x8* src = (const bf16x8*)Wp;
        bf16x8*       dst = (bf16x8*)Blds;
        #pragma unroll
        for (int i = 0; i < 18; ++i)
            dst[t + i*256] = src[t + i*256];
    }
    __syncthreads();

    f32x4 acc[18];
    #pragma unroll
    for (int n = 0; n < 18; ++n) acc[n] = (f32x4){0.f,0.f,0.f,0.f};

    const int   mask  = (l15 & 7) << 4;
    const char* bbase = (const char*)Blds + l15*256;

    #pragma unroll
    for (int s = 0; s < 4; ++s) {
        const char* bs = bbase + ((s*64 + hi*16) ^ mask);
        #pragma unroll
        for (int n = 0; n < 18; ++n) {
            const bf16x8 bfr = *(const bf16x8*)(bs + n*4096);
            acc[n] = __builtin_amdgcn_mfma_f32_16x16x32_bf16(afr[s], bfr, acc[n], 0, 0, 0);
        }
    }

    // epilogue: D row = hi*4 + r (pixel), col = l15 (channel within tile)
    const size_t prow0 = (size_t)gp0 + w*16 + hi*4;
    #pragma unroll
    for (int n = 0; n < 16; ++n) {          // V cols 0..255
        float* vp = Vout + prow0*CS + n*16 + l15;
        #pragma unroll
        for (int r = 0; r < 4; ++r)
            vp[(size_t)r*CS] = acc[n][r];
    }
    #pragma unroll
    for (int n = 16; n < 18; ++n) {         // qk cols -> cost = exp(qk)
        float* cp = costO + prow0*32 + (n-16)*16 + l15;
        #pragma unroll
        for (int r = 0; r < 4; ++r)
            cp[(size_t)r*32] = __expf(acc[n][r]);
    }
}

// ---------- kernel 2: per-output-pixel 9-tap aggregation ----------
__global__ __launch_bounds__(256) void k2_agg(
    const float* __restrict__ cost, const float* __restrict__ V,
    const float* __restrict__ ascale, const float* __restrict__ rpb,
    float* __restrict__ pre)
{
    __shared__ float part[9][32];
    __shared__ float coef[9][8];

    const int blk = blockIdx.x;           // b*784 + ho*28 + wo
    const int b   = blk / NOPIX;
    const int rem = blk % NOPIX;
    const int ho  = rem / WOUT, wo = rem % WOUT;
    const int t   = threadIdx.x;

    int pk[9];
    #pragma unroll
    for (int k = 0; k < 9; ++k) {
        const int ki = k / 3, kj = k % 3;
        const int y  = 2*ho - 1 + ki;
        const int xx = 2*wo - 1 + kj;
        const bool v = ((unsigned)y < (unsigned)HIMG) && ((unsigned)xx < (unsigned)WIMG);
        pk[k] = v ? (y*WIMG + xx) : -1;
    }

    if (t < 32) {
        const int qh = t;
        float den = 0.f;
        float cp[9];
        #pragma unroll
        for (int k = 0; k < 9; ++k) {
            const float s  = (pk[k] >= 0) ? cost[((size_t)(b*NPIX) + pk[k])*32 + qh] : 0.f;
            const float wd = __expf(rpb[k*32 + qh]);
            den  += wd * s;
            cp[k] = wd * ascale[k*32 + qh] * s;
        }
        const float rden = 1.f / den;
        #pragma unroll
        for (int k = 0; k < 9; ++k) part[k][qh] = cp[k] * rden;
    }
    __syncthreads();
    if (t < 72) {
        const int k = t >> 3, h = t & 7;
        coef[k][h] = part[k][h] + part[k][8+h] + part[k][16+h] + part[k][24+h];
    }
    __syncthreads();

    const int h = t >> 5;
    float acc = 0.f;
    #pragma unroll
    for (int k = 0; k < 9; ++k) {
        const int p = (pk[k] >= 0) ? pk[k] : 0;
        const float vv = V[((size_t)(b*NPIX) + p)*CS + t];
        acc = fmaf(coef[k][h], vv, acc);
    }
    pre[(size_t)blk*CS + t] = acc;
}

// ---------- kernel 3: out = Wout @ pre ----------
#define PT3 16
__global__ __launch_bounds__(256) void k3_proj(
    const float* __restrict__ pre, const float* __restrict__ WoutT,
    float* __restrict__ out)
{
    __shared__ __align__(16) float pt[PT3][CS];
    const int t   = threadIdx.x;
    const int g0  = blockIdx.x * PT3;
    const int b   = g0 / NOPIX;
    const int op0 = g0 % NOPIX;

    #pragma unroll
    for (int p = 0; p < PT3; ++p)
        pt[p][t] = pre[((size_t)g0 + p)*CS + t];
    __syncthreads();

    const int o = t;
    float acc[PT3];
    #pragma unroll
    for (int p = 0; p < PT3; ++p) acc[p] = 0.f;

    for (int c4 = 0; c4 < CS; c4 += 4) {
        const float w0 = WoutT[(c4+0)*CS + o];
        const float w1 = WoutT[(c4+1)*CS + o];
        const float w2 = WoutT[(c4+2)*CS + o];
        const float w3 = WoutT[(c4+3)*CS + o];
        #pragma unroll
        for (int p = 0; p < PT3; ++p) {
            const float4 xv = *(const float4*)&pt[p][c4];
            acc[p] = fmaf(xv.x, w0, acc[p]);
            acc[p] = fmaf(xv.y, w1, acc[p]);
            acc[p] = fmaf(xv.z, w2, acc[p]);
            acc[p] = fmaf(xv.w, w3, acc[p]);
        }
    }

    float* obase = out + ((size_t)b*CS + o)*NOPIX + op0;
    #pragma unroll
    for (int p4 = 0; p4 < PT3; p4 += 4)
        *(float4*)(obase + p4) = make_float4(acc[p4], acc[p4+1], acc[p4+2], acc[p4+3]);
}

extern "C" void kernel_launch(void* const* d_in, const int* in_sizes, int n_in,
                              void* d_out, int out_size, void* d_ws, size_t ws_size,
                              hipStream_t stream) {
    const float* x      = (const float*)d_in[0];
    const float* Wk     = (const float*)d_in[1];
    const float* Wv     = (const float*)d_in[2];
    const float* Wout   = (const float*)d_in[3];
    const float* qp     = (const float*)d_in[4];
    const float* ascale = (const float*)d_in[5];
    const float* rpb    = (const float*)d_in[6];
    float* out = (float*)d_out;

    // ws layout (bytes):
    //   cost : 6,422,528 | V: 51,380,224 | pre: 12,845,056 | WoutT: 262,144
    //   xT(bf16): 12,845,056 | Wp(bf16, swizzled): 73,728   -> total ~83.9 MB
    char* ws = (char*)d_ws;
    float*          cost  = (float*)(ws);
    float*          V     = (float*)(ws + 6422528);
    float*          pre   = (float*)(ws + 6422528 + 51380224);
    float*          WoutT = (float*)(ws + 70647808);
    unsigned short* xT    = (unsigned short*)(ws + 70909952);
    unsigned short* Wp    = (unsigned short*)(ws + 83755008);

    k0_transpose<<<CS, 256, 0, stream>>>(Wout, WoutT);
    k0b_foldw   <<<1, 256, 0, stream>>>(Wk, Wv, qp, Wp);
    kT_transpose<<<BATCH*(NPIX/64), 256, 0, stream>>>(x, xT);
    k1_mfma     <<<(BATCH*NPIX)/64, 256, 0, stream>>>(xT, Wp, cost, V);
    k2_agg      <<<BATCH*NOPIX, 256, 0, stream>>>(cost, V, ascale, rpb, pre);
    k3_proj     <<<(BATCH*NOPIX)/PT3, 256, 0, stream>>>(pre, WoutT, out);
}

// Round 4
// 114.616 us; speedup vs baseline: 1.5635x; 1.5635x over previous
//
#include <hip/hip_runtime.h>
#include <hip/hip_bf16.h>

#define BATCH 16
#define CIN   128
#define HIMG  56
#define WIMG  56
#define NPIX  (HIMG*WIMG)      // 3136
#define CS    256
#define NQ    4
#define HOUT  28
#define WOUT  28
#define NOPIX (HOUT*WOUT)      // 784
#define QSCALE 0.17677669529663687f   // hc^-0.5 = 1/sqrt(32)
#define NCOL  288              // 256 V cols + 32 qk cols

typedef __attribute__((ext_vector_type(8))) short  bf16x8;
typedef __attribute__((ext_vector_type(4))) float  f32x4;

static __device__ __forceinline__ unsigned short f2bf(float f) {
    return __builtin_bit_cast(unsigned short, __float2bfloat16(f));
}
static __device__ __forceinline__ unsigned int pack2(float a, float b) {
    return (unsigned)f2bf(a) | ((unsigned)f2bf(b) << 16);
}

// ---------- kernel W: all weight prep, parallel ----------
// blocks 0..15 : WoutT 64x64 transpose tiles
// blocks 16..23: W' rows 0..255 (WvT repack, bf16, XOR-swizzled)
// block  24    : W' rows 256..287 (Wq' = q-folded Wk, bf16, XOR-swizzled)
// W' row n = GEMM column n, 256 bytes; k-byte-offset XORed with ((n&7)<<4)
// so k1's B-frag ds_read_b128 is bank-conflict-free (T2).
__global__ __launch_bounds__(256) void kW_prep(
    const float* __restrict__ Wout, const float* __restrict__ Wk,
    const float* __restrict__ Wv,   const float* __restrict__ qp,
    float* __restrict__ WoutT, unsigned short* __restrict__ Wp)
{
    __shared__ float buf[4352];   // 17 KB, aliased per block role
    const int t   = threadIdx.x;
    const int blk = blockIdx.x;
    char* wp = (char*)Wp;

    if (blk < 16) {
        // ---- WoutT[c][o] = Wout[o][c], 64x64 tile ----
        float (*lt)[65] = (float(*)[65])buf;           // 64*65 = 4160
        const int o0 = (blk & 3) * 64, c0 = (blk >> 2) * 64;
        const int cl = t & 63, ro = t >> 6;
        #pragma unroll
        for (int i = 0; i < 16; ++i) {
            const int o = ro + i*4;
            lt[o][cl] = Wout[(size_t)(o0+o)*CS + c0 + cl];
        }
        __syncthreads();
        #pragma unroll
        for (int i = 0; i < 16; ++i) {
            const int c = ro + i*4;
            WoutT[(size_t)(c0+c)*CS + o0 + cl] = lt[cl][c];
        }
    } else if (blk < 24) {
        // ---- WvT repack: W' row ch holds Wv[*, ch] as bf16 pairs ----
        float (*lt)[33] = (float(*)[33])buf;           // 128*33 = 4224
        const int ch0 = (blk - 16) * 32;
        const int j = t & 31, r = t >> 5;              // r = 0..7
        #pragma unroll
        for (int pass = 0; pass < 16; ++pass) {
            const int c = r + pass*8;
            lt[c][j] = Wv[(size_t)c*CS + ch0 + j];     // coalesced 128B/row
        }
        __syncthreads();
        const int lch = t >> 3, sub = t & 7;
        const int ch  = ch0 + lch;
        const int mask = (ch & 7) << 4;
        #pragma unroll
        for (int i = 0; i < 8; ++i) {
            const int c2 = sub*8 + i;
            const unsigned u = pack2(lt[2*c2][lch], lt[2*c2+1][lch]);
            *(unsigned*)(wp + ch*256 + ((c2*4) ^ mask)) = u;
        }
    } else {
        // ---- Wq'[qh][c] = sum_j Wk[c][h*32+j] * q[q][h*32+j] * QSCALE ----
        float* qs = buf;                               // 1024 floats
        for (int i = t; i < NQ*CS; i += 256) qs[i] = qp[i] * QSCALE;
        __syncthreads();
        const int qh = t >> 3, kg = t & 7;             // 32 rows x 8 k-groups
        const int h = qh & 7, q = qh >> 3;
        const int row = 256 + qh;
        const int mask = (qh & 7) << 4;                // == (row&7)<<4
        const float* qv = &qs[q*CS + h*32];
        #pragma unroll
        for (int i = 0; i < 8; ++i) {
            const int c2 = kg*8 + i;
            float d0 = 0.f, d1 = 0.f;
            const float* wk0 = Wk + (size_t)(2*c2)*CS + h*32;
            const float* wk1 = wk0 + CS;
            #pragma unroll
            for (int j4 = 0; j4 < 32; j4 += 4) {
                const float4 a0 = *(const float4*)(wk0 + j4);
                const float4 a1 = *(const float4*)(wk1 + j4);
                const float4 qq = *(const float4*)(qv + j4);
                d0 = fmaf(a0.x, qq.x, d0); d0 = fmaf(a0.y, qq.y, d0);
                d0 = fmaf(a0.z, qq.z, d0); d0 = fmaf(a0.w, qq.w, d0);
                d1 = fmaf(a1.x, qq.x, d1); d1 = fmaf(a1.y, qq.y, d1);
                d1 = fmaf(a1.z, qq.z, d1); d1 = fmaf(a1.w, qq.w, d1);
            }
            *(unsigned*)(wp + row*256 + ((c2*4) ^ mask)) = pack2(d0, d1);
        }
    }
}

// ---------- kernel T: x (B,C,N) f32 -> xT (B*N, 128) bf16 ----------
__global__ __launch_bounds__(256) void kT_transpose(
    const float* __restrict__ x, unsigned short* __restrict__ xT)
{
    __shared__ float lt[CIN][66];   // +2 pad
    const int t   = threadIdx.x;
    const int blk = blockIdx.x;            // b*49 + ptile
    const int b   = blk / (NPIX/64);
    const int p0  = (blk % (NPIX/64)) * 64;

    {   // load 128c x 64p tile, coalesced float4
        const int c0 = t >> 4;             // 0..15
        const int f4 = t & 15;             // 16 float4 per row
        #pragma unroll
        for (int i = 0; i < 8; ++i) {
            const int c = c0 + i*16;
            const float4 v = *(const float4*)(x + ((size_t)b*CIN + c)*NPIX + p0 + f4*4);
            lt[c][f4*4+0] = v.x; lt[c][f4*4+1] = v.y;
            lt[c][f4*4+2] = v.z; lt[c][f4*4+3] = v.w;
        }
    }
    __syncthreads();

    const int p = t >> 2, seg = t & 3;
    unsigned short* orow = xT + ((size_t)(b*NPIX) + p0 + p)*CIN + seg*32;
    #pragma unroll
    for (int g = 0; g < 4; ++g) {          // 8 c per 16B store
        const int c0 = seg*32 + g*8;
        uint4 u;
        u.x = pack2(lt[c0+0][p], lt[c0+1][p]);
        u.y = pack2(lt[c0+2][p], lt[c0+3][p]);
        u.z = pack2(lt[c0+4][p], lt[c0+5][p]);
        u.w = pack2(lt[c0+6][p], lt[c0+7][p]);
        *(uint4*)(orow + g*8) = u;
    }
}

// ---------- kernel 1: MFMA GEMM xT(50176x128) @ W'(128x288) -> V + cost ----------
__global__ __launch_bounds__(256, 2) void k1_mfma(
    const unsigned short* __restrict__ xT, const unsigned short* __restrict__ Wp,
    float* __restrict__ costO, float* __restrict__ Vout)
{
    __shared__ unsigned short Blds[NCOL*CIN];   // 73728 B

    const int t    = threadIdx.x;
    const int lane = t & 63;
    const int w    = t >> 6;
    const int l15  = lane & 15;
    const int hi   = lane >> 4;
    const int gp0  = blockIdx.x * 64;

    const unsigned short* arow = xT + ((size_t)(gp0 + w*16 + l15))*CIN + hi*8;
    bf16x8 afr[4];
    #pragma unroll
    for (int s = 0; s < 4; ++s)
        afr[s] = *(const bf16x8*)(arow + s*32);

    {   // stage B: linear copy of pre-swizzled image (L2-resident)
        const bf16x8* src = (const bf16x8*)Wp;
        bf16x8*       dst = (bf16x8*)Blds;
        #pragma unroll
        for (int i = 0; i < 18; ++i)
            dst[t + i*256] = src[t + i*256];
    }
    __syncthreads();

    f32x4 acc[18];
    #pragma unroll
    for (int n = 0; n < 18; ++n) acc[n] = (f32x4){0.f,0.f,0.f,0.f};

    const int   mask  = (l15 & 7) << 4;
    const char* bbase = (const char*)Blds + l15*256;

    #pragma unroll
    for (int s = 0; s < 4; ++s) {
        const char* bs = bbase + ((s*64 + hi*16) ^ mask);
        #pragma unroll
        for (int n = 0; n < 18; ++n) {
            const bf16x8 bfr = *(const bf16x8*)(bs + n*4096);
            acc[n] = __builtin_amdgcn_mfma_f32_16x16x32_bf16(afr[s], bfr, acc[n], 0, 0, 0);
        }
    }

    const size_t prow0 = (size_t)gp0 + w*16 + hi*4;
    #pragma unroll
    for (int n = 0; n < 16; ++n) {          // V cols
        float* vp = Vout + prow0*CS + n*16 + l15;
        #pragma unroll
        for (int r = 0; r < 4; ++r)
            vp[(size_t)r*CS] = acc[n][r];
    }
    #pragma unroll
    for (int n = 16; n < 18; ++n) {         // qk cols -> cost = exp(qk)
        float* cp = costO + prow0*32 + (n-16)*16 + l15;
        #pragma unroll
        for (int r = 0; r < 4; ++r)
            cp[(size_t)r*32] = __expf(acc[n][r]);
    }
}

// ---------- kernel 2: per-output-pixel 9-tap aggregation ----------
__global__ __launch_bounds__(256) void k2_agg(
    const float* __restrict__ cost, const float* __restrict__ V,
    const float* __restrict__ ascale, const float* __restrict__ rpb,
    float* __restrict__ pre)
{
    __shared__ float part[9][32];
    __shared__ float coef[9][8];

    const int blk = blockIdx.x;           // b*784 + ho*28 + wo
    const int b   = blk / NOPIX;
    const int rem = blk % NOPIX;
    const int ho  = rem / WOUT, wo = rem % WOUT;
    const int t   = threadIdx.x;

    int pk[9];
    #pragma unroll
    for (int k = 0; k < 9; ++k) {
        const int ki = k / 3, kj = k % 3;
        const int y  = 2*ho - 1 + ki;
        const int xx = 2*wo - 1 + kj;
        const bool v = ((unsigned)y < (unsigned)HIMG) && ((unsigned)xx < (unsigned)WIMG);
        pk[k] = v ? (y*WIMG + xx) : -1;
    }

    if (t < 32) {
        const int qh = t;
        float den = 0.f;
        float cp[9];
        #pragma unroll
        for (int k = 0; k < 9; ++k) {
            const float s  = (pk[k] >= 0) ? cost[((size_t)(b*NPIX) + pk[k])*32 + qh] : 0.f;
            const float wd = __expf(rpb[k*32 + qh]);
            den  += wd * s;
            cp[k] = wd * ascale[k*32 + qh] * s;
        }
        const float rden = 1.f / den;
        #pragma unroll
        for (int k = 0; k < 9; ++k) part[k][qh] = cp[k] * rden;
    }
    __syncthreads();
    if (t < 72) {
        const int k = t >> 3, h = t & 7;
        coef[k][h] = part[k][h] + part[k][8+h] + part[k][16+h] + part[k][24+h];
    }
    __syncthreads();

    const int h = t >> 5;
    float acc = 0.f;
    #pragma unroll
    for (int k = 0; k < 9; ++k) {
        const int p = (pk[k] >= 0) ? pk[k] : 0;
        const float vv = V[((size_t)(b*NPIX) + p)*CS + t];
        acc = fmaf(coef[k][h], vv, acc);
    }
    pre[(size_t)blk*CS + t] = acc;
}

// ---------- kernel 3: out = Wout @ pre ----------
#define PT3 16
__global__ __launch_bounds__(256) void k3_proj(
    const float* __restrict__ pre, const float* __restrict__ WoutT,
    float* __restrict__ out)
{
    __shared__ __align__(16) float pt[PT3][CS];
    const int t   = threadIdx.x;
    const int g0  = blockIdx.x * PT3;
    const int b   = g0 / NOPIX;
    const int op0 = g0 % NOPIX;

    #pragma unroll
    for (int p = 0; p < PT3; ++p)
        pt[p][t] = pre[((size_t)g0 + p)*CS + t];
    __syncthreads();

    const int o = t;
    float acc[PT3];
    #pragma unroll
    for (int p = 0; p < PT3; ++p) acc[p] = 0.f;

    for (int c4 = 0; c4 < CS; c4 += 4) {
        const float w0 = WoutT[(c4+0)*CS + o];
        const float w1 = WoutT[(c4+1)*CS + o];
        const float w2 = WoutT[(c4+2)*CS + o];
        const float w3 = WoutT[(c4+3)*CS + o];
        #pragma unroll
        for (int p = 0; p < PT3; ++p) {
            const float4 xv = *(const float4*)&pt[p][c4];
            acc[p] = fmaf(xv.x, w0, acc[p]);
            acc[p] = fmaf(xv.y, w1, acc[p]);
            acc[p] = fmaf(xv.z, w2, acc[p]);
            acc[p] = fmaf(xv.w, w3, acc[p]);
        }
    }

    float* obase = out + ((size_t)b*CS + o)*NOPIX + op0;
    #pragma unroll
    for (int p4 = 0; p4 < PT3; p4 += 4)
        *(float4*)(obase + p4) = make_float4(acc[p4], acc[p4+1], acc[p4+2], acc[p4+3]);
}

extern "C" void kernel_launch(void* const* d_in, const int* in_sizes, int n_in,
                              void* d_out, int out_size, void* d_ws, size_t ws_size,
                              hipStream_t stream) {
    const float* x      = (const float*)d_in[0];
    const float* Wk     = (const float*)d_in[1];
    const float* Wv     = (const float*)d_in[2];
    const float* Wout   = (const float*)d_in[3];
    const float* qp     = (const float*)d_in[4];
    const float* ascale = (const float*)d_in[5];
    const float* rpb    = (const float*)d_in[6];
    float* out = (float*)d_out;

    // ws layout (bytes):
    //   cost: 6,422,528 | V: 51,380,224 | pre: 12,845,056 | WoutT: 262,144
    //   xT(bf16): 12,845,056 | Wp(bf16, swizzled): 73,728   -> ~83.9 MB
    char* ws = (char*)d_ws;
    float*          cost  = (float*)(ws);
    float*          V     = (float*)(ws + 6422528);
    float*          pre   = (float*)(ws + 6422528 + 51380224);
    float*          WoutT = (float*)(ws + 70647808);
    unsigned short* xT    = (unsigned short*)(ws + 70909952);
    unsigned short* Wp    = (unsigned short*)(ws + 83755008);

    kW_prep     <<<25, 256, 0, stream>>>(Wout, Wk, Wv, qp, WoutT, Wp);
    kT_transpose<<<BATCH*(NPIX/64), 256, 0, stream>>>(x, xT);
    k1_mfma     <<<(BATCH*NPIX)/64, 256, 0, stream>>>(xT, Wp, cost, V);
    k2_agg      <<<BATCH*NOPIX, 256, 0, stream>>>(cost, V, ascale, rpb, pre);
    k3_proj     <<<(BATCH*NOPIX)/PT3, 256, 0, stream>>>(pre, WoutT, out);
}

// Round 5
// 79.761 us; speedup vs baseline: 2.2467x; 1.4370x over previous
//
#include <hip/hip_runtime.h>
#include <hip/hip_bf16.h>

#define BATCH 16
#define CIN   128
#define HIMG  56
#define WIMG  56
#define NPIX  (HIMG*WIMG)      // 3136
#define CS    256
#define NQ    4
#define HOUT  28
#define WOUT  28
#define NOPIX (HOUT*WOUT)      // 784
#define QSCALE 0.17677669529663687f   // hc^-0.5 = 1/sqrt(32)
#define NCOL  288              // 256 V cols + 32 qk cols

typedef __attribute__((ext_vector_type(8))) short  bf16x8;
typedef __attribute__((ext_vector_type(4))) float  f32x4;

static __device__ __forceinline__ unsigned short f2bf(float f) {
    return __builtin_bit_cast(unsigned short, __float2bfloat16(f));
}
static __device__ __forceinline__ float bf2f(unsigned short u) {
    return __builtin_bit_cast(float, (unsigned)u << 16);
}
static __device__ __forceinline__ unsigned int pack2(float a, float b) {
    return (unsigned)f2bf(a) | ((unsigned)f2bf(b) << 16);
}

// ---------- kernel W: all weight prep, parallel ----------
// blocks 0..7  : Wout -> WoutHi/WoutLo bf16 split (hi + residual)
// blocks 8..15 : W' rows 0..255 (WvT repack, bf16, XOR-swizzled)
// block  16    : W' rows 256..287 (Wq' = q-folded Wk, bf16, XOR-swizzled)
__global__ __launch_bounds__(256) void kW_prep(
    const float* __restrict__ Wout, const float* __restrict__ Wk,
    const float* __restrict__ Wv,   const float* __restrict__ qp,
    unsigned short* __restrict__ WHi, unsigned short* __restrict__ WLo,
    unsigned short* __restrict__ Wp)
{
    __shared__ float buf[4352];   // 17 KB, aliased per block role
    const int t   = threadIdx.x;
    const int blk = blockIdx.x;
    char* wp = (char*)Wp;

    if (blk < 8) {
        // ---- Wout hi/lo split, coalesced ----
        const size_t base = (size_t)blk * 8192 + t;
        #pragma unroll
        for (int i = 0; i < 32; ++i) {
            const float f = Wout[base + i*256];
            const unsigned short h = f2bf(f);
            WHi[base + i*256] = h;
            WLo[base + i*256] = f2bf(f - bf2f(h));
        }
    } else if (blk < 16) {
        // ---- WvT repack: W' row ch holds Wv[*, ch] as bf16 pairs ----
        float (*lt)[33] = (float(*)[33])buf;           // 128*33 = 4224
        const int ch0 = (blk - 8) * 32;
        const int j = t & 31, r = t >> 5;              // r = 0..7
        #pragma unroll
        for (int pass = 0; pass < 16; ++pass) {
            const int c = r + pass*8;
            lt[c][j] = Wv[(size_t)c*CS + ch0 + j];     // coalesced 128B/row
        }
        __syncthreads();
        const int lch = t >> 3, sub = t & 7;
        const int ch  = ch0 + lch;
        const int mask = (ch & 7) << 4;
        #pragma unroll
        for (int i = 0; i < 8; ++i) {
            const int c2 = sub*8 + i;
            const unsigned u = pack2(lt[2*c2][lch], lt[2*c2+1][lch]);
            *(unsigned*)(wp + ch*256 + ((c2*4) ^ mask)) = u;
        }
    } else {
        // ---- Wq'[qh][c] = sum_j Wk[c][h*32+j] * q[q][h*32+j] * QSCALE ----
        float* qs = buf;                               // 1024 floats
        for (int i = t; i < NQ*CS; i += 256) qs[i] = qp[i] * QSCALE;
        __syncthreads();
        const int qh = t >> 3, kg = t & 7;             // 32 rows x 8 k-groups
        const int h = qh & 7, q = qh >> 3;
        const int row = 256 + qh;
        const int mask = (qh & 7) << 4;                // == (row&7)<<4
        const float* qv = &qs[q*CS + h*32];
        #pragma unroll
        for (int i = 0; i < 8; ++i) {
            const int c2 = kg*8 + i;
            float d0 = 0.f, d1 = 0.f;
            const float* wk0 = Wk + (size_t)(2*c2)*CS + h*32;
            const float* wk1 = wk0 + CS;
            #pragma unroll
            for (int j4 = 0; j4 < 32; j4 += 4) {
                const float4 a0 = *(const float4*)(wk0 + j4);
                const float4 a1 = *(const float4*)(wk1 + j4);
                const float4 qq = *(const float4*)(qv + j4);
                d0 = fmaf(a0.x, qq.x, d0); d0 = fmaf(a0.y, qq.y, d0);
                d0 = fmaf(a0.z, qq.z, d0); d0 = fmaf(a0.w, qq.w, d0);
                d1 = fmaf(a1.x, qq.x, d1); d1 = fmaf(a1.y, qq.y, d1);
                d1 = fmaf(a1.z, qq.z, d1); d1 = fmaf(a1.w, qq.w, d1);
            }
            *(unsigned*)(wp + row*256 + ((c2*4) ^ mask)) = pack2(d0, d1);
        }
    }
}

// ---------- kernel T: x (B,C,N) f32 -> xT (B*N, 128) bf16 ----------
__global__ __launch_bounds__(256) void kT_transpose(
    const float* __restrict__ x, unsigned short* __restrict__ xT)
{
    __shared__ float lt[CIN][66];   // +2 pad
    const int t   = threadIdx.x;
    const int blk = blockIdx.x;            // b*49 + ptile
    const int b   = blk / (NPIX/64);
    const int p0  = (blk % (NPIX/64)) * 64;

    {   // load 128c x 64p tile, coalesced float4
        const int c0 = t >> 4;             // 0..15
        const int f4 = t & 15;             // 16 float4 per row
        #pragma unroll
        for (int i = 0; i < 8; ++i) {
            const int c = c0 + i*16;
            const float4 v = *(const float4*)(x + ((size_t)b*CIN + c)*NPIX + p0 + f4*4);
            lt[c][f4*4+0] = v.x; lt[c][f4*4+1] = v.y;
            lt[c][f4*4+2] = v.z; lt[c][f4*4+3] = v.w;
        }
    }
    __syncthreads();

    const int p = t >> 2, seg = t & 3;
    unsigned short* orow = xT + ((size_t)(b*NPIX) + p0 + p)*CIN + seg*32;
    #pragma unroll
    for (int g = 0; g < 4; ++g) {          // 8 c per 16B store
        const int c0 = seg*32 + g*8;
        uint4 u;
        u.x = pack2(lt[c0+0][p], lt[c0+1][p]);
        u.y = pack2(lt[c0+2][p], lt[c0+3][p]);
        u.z = pack2(lt[c0+4][p], lt[c0+5][p]);
        u.w = pack2(lt[c0+6][p], lt[c0+7][p]);
        *(uint4*)(orow + g*8) = u;
    }
}

// ---------- kernel 1: MFMA GEMM xT(50176x128) @ W'(128x288) -> V(bf16) + cost ----------
__global__ __launch_bounds__(256, 2) void k1_mfma(
    const unsigned short* __restrict__ xT, const unsigned short* __restrict__ Wp,
    float* __restrict__ costO, unsigned short* __restrict__ Vout)
{
    __shared__ unsigned short Blds[NCOL*CIN];   // 73728 B

    const int t    = threadIdx.x;
    const int lane = t & 63;
    const int w    = t >> 6;
    const int l15  = lane & 15;
    const int hi   = lane >> 4;
    const int gp0  = blockIdx.x * 64;

    const unsigned short* arow = xT + ((size_t)(gp0 + w*16 + l15))*CIN + hi*8;
    bf16x8 afr[4];
    #pragma unroll
    for (int s = 0; s < 4; ++s)
        afr[s] = *(const bf16x8*)(arow + s*32);

    {   // stage B: linear copy of pre-swizzled image (L2-resident)
        const bf16x8* src = (const bf16x8*)Wp;
        bf16x8*       dst = (bf16x8*)Blds;
        #pragma unroll
        for (int i = 0; i < 18; ++i)
            dst[t + i*256] = src[t + i*256];
    }
    __syncthreads();

    f32x4 acc[18];
    #pragma unroll
    for (int n = 0; n < 18; ++n) acc[n] = (f32x4){0.f,0.f,0.f,0.f};

    const int   mask  = (l15 & 7) << 4;
    const char* bbase = (const char*)Blds + l15*256;

    #pragma unroll
    for (int s = 0; s < 4; ++s) {
        const char* bs = bbase + ((s*64 + hi*16) ^ mask);
        #pragma unroll
        for (int n = 0; n < 18; ++n) {
            const bf16x8 bfr = *(const bf16x8*)(bs + n*4096);
            acc[n] = __builtin_amdgcn_mfma_f32_16x16x32_bf16(afr[s], bfr, acc[n], 0, 0, 0);
        }
    }

    const size_t prow0 = (size_t)gp0 + w*16 + hi*4;
    #pragma unroll
    for (int n = 0; n < 16; ++n) {          // V cols, bf16 (L2 merges short stores)
        unsigned short* vp = Vout + prow0*CS + n*16 + l15;
        #pragma unroll
        for (int r = 0; r < 4; ++r)
            vp[(size_t)r*CS] = f2bf(acc[n][r]);
    }
    #pragma unroll
    for (int n = 16; n < 18; ++n) {         // qk cols -> cost = exp(qk)
        float* cp = costO + prow0*32 + (n-16)*16 + l15;
        #pragma unroll
        for (int r = 0; r < 4; ++r)
            cp[(size_t)r*32] = __expf(acc[n][r]);
    }
}

// ---------- kernel 2: per-output-pixel 9-tap aggregation (V bf16 -> pre bf16) ----------
__global__ __launch_bounds__(256) void k2_agg(
    const float* __restrict__ cost, const unsigned short* __restrict__ V,
    const float* __restrict__ ascale, const float* __restrict__ rpb,
    unsigned short* __restrict__ pre)
{
    __shared__ float part[9][32];
    __shared__ float coef[9][8];

    const int blk = blockIdx.x;           // b*784 + ho*28 + wo
    const int b   = blk / NOPIX;
    const int rem = blk % NOPIX;
    const int ho  = rem / WOUT, wo = rem % WOUT;
    const int t   = threadIdx.x;

    int pk[9];
    #pragma unroll
    for (int k = 0; k < 9; ++k) {
        const int ki = k / 3, kj = k % 3;
        const int y  = 2*ho - 1 + ki;
        const int xx = 2*wo - 1 + kj;
        const bool v = ((unsigned)y < (unsigned)HIMG) && ((unsigned)xx < (unsigned)WIMG);
        pk[k] = v ? (y*WIMG + xx) : -1;
    }

    if (t < 32) {
        const int qh = t;
        float den = 0.f;
        float cp[9];
        #pragma unroll
        for (int k = 0; k < 9; ++k) {
            const float s  = (pk[k] >= 0) ? cost[((size_t)(b*NPIX) + pk[k])*32 + qh] : 0.f;
            const float wd = __expf(rpb[k*32 + qh]);
            den  += wd * s;
            cp[k] = wd * ascale[k*32 + qh] * s;
        }
        const float rden = 1.f / den;
        #pragma unroll
        for (int k = 0; k < 9; ++k) part[k][qh] = cp[k] * rden;
    }
    __syncthreads();
    if (t < 72) {
        const int k = t >> 3, h = t & 7;
        coef[k][h] = part[k][h] + part[k][8+h] + part[k][16+h] + part[k][24+h];
    }
    __syncthreads();

    const int h = t >> 5;
    float acc = 0.f;
    #pragma unroll
    for (int k = 0; k < 9; ++k) {
        const int p = (pk[k] >= 0) ? pk[k] : 0;
        const float vv = bf2f(V[((size_t)(b*NPIX) + p)*CS + t]);
        acc = fmaf(coef[k][h], vv, acc);
    }
    pre[(size_t)blk*CS + t] = f2bf(acc);
}

// ---------- kernel 3: out = Wout @ pre^T via MFMA, hi/lo split A (f32-accurate) ----------
// Block = 64 o x 112 pixels, 4 waves (wave w: o-range w*16). No LDS: A/B frags
// straight from global (Wout-split 512KB + pre rows, all L2-resident).
__global__ __launch_bounds__(256) void k3_mfma(
    const unsigned short* __restrict__ pre, const unsigned short* __restrict__ WHi,
    const unsigned short* __restrict__ WLo, float* __restrict__ out)
{
    const int t    = threadIdx.x;
    const int lane = t & 63;
    const int w    = t >> 6;
    const int l15  = lane & 15;
    const int hi   = lane >> 4;
    const int blk  = blockIdx.x;           // b*28 + otile*7 + ptile
    const int b    = blk / 28;
    const int rem  = blk % 28;
    const int o0   = (rem / 7) * 64 + w * 16;
    const int p0   = (rem % 7) * 112;

    bf16x8 aH[8], aL[8];
    {
        const unsigned short* ah = WHi + (size_t)(o0 + l15)*CS + hi*8;
        const unsigned short* al = WLo + (size_t)(o0 + l15)*CS + hi*8;
        #pragma unroll
        for (int s = 0; s < 8; ++s) {
            aH[s] = *(const bf16x8*)(ah + s*32);
            aL[s] = *(const bf16x8*)(al + s*32);
        }
    }

    const unsigned short* bbase = pre + ((size_t)(b*NOPIX) + p0 + l15)*CS + hi*8;

    f32x4 acc[7];
    #pragma unroll
    for (int n = 0; n < 7; ++n) acc[n] = (f32x4){0.f,0.f,0.f,0.f};

    #pragma unroll
    for (int n = 0; n < 7; ++n) {
        const unsigned short* bn = bbase + (size_t)(n*16)*CS;
        bf16x8 bf[8];
        #pragma unroll
        for (int s = 0; s < 8; ++s) bf[s] = *(const bf16x8*)(bn + s*32);
        #pragma unroll
        for (int s = 0; s < 8; ++s) {
            acc[n] = __builtin_amdgcn_mfma_f32_16x16x32_bf16(aH[s], bf[s], acc[n], 0, 0, 0);
            acc[n] = __builtin_amdgcn_mfma_f32_16x16x32_bf16(aL[s], bf[s], acc[n], 0, 0, 0);
        }
    }

    // D: row = o (hi*4+r), col = pixel (l15) -> 64B-coalesced stores per (n,r)
    #pragma unroll
    for (int n = 0; n < 7; ++n) {
        #pragma unroll
        for (int r = 0; r < 4; ++r)
            out[((size_t)(b*CS) + o0 + hi*4 + r)*NOPIX + p0 + n*16 + l15] = acc[n][r];
    }
}

extern "C" void kernel_launch(void* const* d_in, const int* in_sizes, int n_in,
                              void* d_out, int out_size, void* d_ws, size_t ws_size,
                              hipStream_t stream) {
    const float* x      = (const float*)d_in[0];
    const float* Wk     = (const float*)d_in[1];
    const float* Wv     = (const float*)d_in[2];
    const float* Wout   = (const float*)d_in[3];
    const float* qp     = (const float*)d_in[4];
    const float* ascale = (const float*)d_in[5];
    const float* rpb    = (const float*)d_in[6];
    float* out = (float*)d_out;

    // ws layout (bytes):
    //   cost f32 : 6,422,528
    //   V bf16   : 25,690,112
    //   pre bf16 : 6,422,528
    //   xT bf16  : 12,845,056
    //   WoutHi   : 131,072 | WoutLo: 131,072 | Wp: 73,728   -> ~51.7 MB
    char* ws = (char*)d_ws;
    float*          cost = (float*)(ws);
    unsigned short* V    = (unsigned short*)(ws + 6422528);
    unsigned short* pre  = (unsigned short*)(ws + 32112640);
    unsigned short* xT   = (unsigned short*)(ws + 38535168);
    unsigned short* WHi  = (unsigned short*)(ws + 51380224);
    unsigned short* WLo  = (unsigned short*)(ws + 51511296);
    unsigned short* Wp   = (unsigned short*)(ws + 51642368);

    kW_prep     <<<17, 256, 0, stream>>>(Wout, Wk, Wv, qp, WHi, WLo, Wp);
    kT_transpose<<<BATCH*(NPIX/64), 256, 0, stream>>>(x, xT);
    k1_mfma     <<<(BATCH*NPIX)/64, 256, 0, stream>>>(xT, Wp, cost, V);
    k2_agg      <<<BATCH*NOPIX, 256, 0, stream>>>(cost, V, ascale, rpb, pre);
    k3_mfma     <<<BATCH*28, 256, 0, stream>>>(pre, WHi, WLo, out);
}

// Round 6
// 67.790 us; speedup vs baseline: 2.6434x; 1.1766x over previous
//
#include <hip/hip_runtime.h>
#include <hip/hip_bf16.h>

#define BATCH 16
#define CIN   128
#define HIMG  56
#define WIMG  56
#define NPIX  (HIMG*WIMG)      // 3136
#define CS    256
#define NQ    4
#define HOUT  28
#define WOUT  28
#define NOPIX (HOUT*WOUT)      // 784
#define QSCALE 0.17677669529663687f   // hc^-0.5 = 1/sqrt(32)
#define NCOL  288              // 256 V cols + 32 qk cols

typedef __attribute__((ext_vector_type(8))) short    bf16x8;
typedef __attribute__((ext_vector_type(4))) float    f32x4;
typedef __attribute__((ext_vector_type(4))) unsigned u32x4;

static __device__ __forceinline__ unsigned short f2bf(float f) {
    return __builtin_bit_cast(unsigned short, __float2bfloat16(f));
}
static __device__ __forceinline__ float bf2f(unsigned short u) {
    return __builtin_bit_cast(float, (unsigned)u << 16);
}
static __device__ __forceinline__ unsigned int pack2(float a, float b) {
    return (unsigned)f2bf(a) | ((unsigned)f2bf(b) << 16);
}

// ---------- kernel W: all weight prep, parallel ----------
// blocks 0..7  : Wout -> WoutHi/WoutLo bf16 split (hi + residual)
// blocks 8..15 : W' rows 0..255 (WvT repack, bf16, XOR-swizzled)
// block  16    : W' rows 256..287 (Wq' = q-folded Wk, bf16, XOR-swizzled)
__global__ __launch_bounds__(256) void kW_prep(
    const float* __restrict__ Wout, const float* __restrict__ Wk,
    const float* __restrict__ Wv,   const float* __restrict__ qp,
    unsigned short* __restrict__ WHi, unsigned short* __restrict__ WLo,
    unsigned short* __restrict__ Wp)
{
    __shared__ float buf[4352];   // 17 KB, aliased per block role
    const int t   = threadIdx.x;
    const int blk = blockIdx.x;
    char* wp = (char*)Wp;

    if (blk < 8) {
        // ---- Wout hi/lo split, coalesced ----
        const size_t base = (size_t)blk * 8192 + t;
        #pragma unroll
        for (int i = 0; i < 32; ++i) {
            const float f = Wout[base + i*256];
            const unsigned short h = f2bf(f);
            WHi[base + i*256] = h;
            WLo[base + i*256] = f2bf(f - bf2f(h));
        }
    } else if (blk < 16) {
        // ---- WvT repack: W' row ch holds Wv[*, ch] as bf16 pairs ----
        float (*lt)[33] = (float(*)[33])buf;           // 128*33 = 4224
        const int ch0 = (blk - 8) * 32;
        const int j = t & 31, r = t >> 5;              // r = 0..7
        #pragma unroll
        for (int pass = 0; pass < 16; ++pass) {
            const int c = r + pass*8;
            lt[c][j] = Wv[(size_t)c*CS + ch0 + j];     // coalesced 128B/row
        }
        __syncthreads();
        const int lch = t >> 3, sub = t & 7;
        const int ch  = ch0 + lch;
        const int mask = (ch & 7) << 4;
        #pragma unroll
        for (int i = 0; i < 8; ++i) {
            const int c2 = sub*8 + i;
            const unsigned u = pack2(lt[2*c2][lch], lt[2*c2+1][lch]);
            *(unsigned*)(wp + ch*256 + ((c2*4) ^ mask)) = u;
        }
    } else {
        // ---- Wq'[qh][c] = sum_j Wk[c][h*32+j] * q[q][h*32+j] * QSCALE ----
        float* qs = buf;                               // 1024 floats
        for (int i = t; i < NQ*CS; i += 256) qs[i] = qp[i] * QSCALE;
        __syncthreads();
        const int qh = t >> 3, kg = t & 7;             // 32 rows x 8 k-groups
        const int h = qh & 7, q = qh >> 3;
        const int row = 256 + qh;
        const int mask = (qh & 7) << 4;                // == (row&7)<<4
        const float* qv = &qs[q*CS + h*32];
        #pragma unroll
        for (int i = 0; i < 8; ++i) {
            const int c2 = kg*8 + i;
            float d0 = 0.f, d1 = 0.f;
            const float* wk0 = Wk + (size_t)(2*c2)*CS + h*32;
            const float* wk1 = wk0 + CS;
            #pragma unroll
            for (int j4 = 0; j4 < 32; j4 += 4) {
                const float4 a0 = *(const float4*)(wk0 + j4);
                const float4 a1 = *(const float4*)(wk1 + j4);
                const float4 qq = *(const float4*)(qv + j4);
                d0 = fmaf(a0.x, qq.x, d0); d0 = fmaf(a0.y, qq.y, d0);
                d0 = fmaf(a0.z, qq.z, d0); d0 = fmaf(a0.w, qq.w, d0);
                d1 = fmaf(a1.x, qq.x, d1); d1 = fmaf(a1.y, qq.y, d1);
                d1 = fmaf(a1.z, qq.z, d1); d1 = fmaf(a1.w, qq.w, d1);
            }
            *(unsigned*)(wp + row*256 + ((c2*4) ^ mask)) = pack2(d0, d1);
        }
    }
}

// ---------- kernel 1: fused transpose+GEMM: x(f32, B,C,N) @ W'(128x288) ----------
// A-frags loaded straight from x: for fixed channel, 16 consecutive pixels are
// one 64B sector (lane l15 = pixel) -> 32 coalesced dword loads per thread,
// converted to bf16 in registers. No xT buffer, no kT kernel.
__global__ __launch_bounds__(256, 2) void k1_mfma(
    const float* __restrict__ x, const unsigned short* __restrict__ Wp,
    float* __restrict__ costO, unsigned short* __restrict__ Vout)
{
    __shared__ unsigned short Blds[NCOL*CIN];   // 73728 B

    const int t    = threadIdx.x;
    const int lane = t & 63;
    const int w    = t >> 6;
    const int l15  = lane & 15;
    const int hi   = lane >> 4;
    const int gp0  = blockIdx.x * 64;           // 64-pixel tile, never crosses batch
    const int b    = gp0 / NPIX;
    const int p    = gp0 - b*NPIX + w*16 + l15;

    // issue A loads (32 dwords, 16-lane coalesced into 64B sectors)
    float av[4][8];
    {
        const float* xb = x + (size_t)b*CIN*NPIX + (size_t)(hi*8)*NPIX + p;
        #pragma unroll
        for (int s = 0; s < 4; ++s)
            #pragma unroll
            for (int j = 0; j < 8; ++j)
                av[s][j] = xb[(size_t)(s*32 + j)*NPIX];
    }

    {   // stage B: linear copy of pre-swizzled image (L2-resident)
        const bf16x8* src = (const bf16x8*)Wp;
        bf16x8*       dst = (bf16x8*)Blds;
        #pragma unroll
        for (int i = 0; i < 18; ++i)
            dst[t + i*256] = src[t + i*256];
    }

    // pack A to bf16 frags while B writes drain
    bf16x8 afr[4];
    #pragma unroll
    for (int s = 0; s < 4; ++s) {
        u32x4 u;
        u[0] = pack2(av[s][0], av[s][1]);
        u[1] = pack2(av[s][2], av[s][3]);
        u[2] = pack2(av[s][4], av[s][5]);
        u[3] = pack2(av[s][6], av[s][7]);
        afr[s] = __builtin_bit_cast(bf16x8, u);
    }
    __syncthreads();

    f32x4 acc[18];
    #pragma unroll
    for (int n = 0; n < 18; ++n) acc[n] = (f32x4){0.f,0.f,0.f,0.f};

    const int   mask  = (l15 & 7) << 4;
    const char* bbase = (const char*)Blds + l15*256;

    #pragma unroll
    for (int s = 0; s < 4; ++s) {
        const char* bs = bbase + ((s*64 + hi*16) ^ mask);
        #pragma unroll
        for (int n = 0; n < 18; ++n) {
            const bf16x8 bfr = *(const bf16x8*)(bs + n*4096);
            acc[n] = __builtin_amdgcn_mfma_f32_16x16x32_bf16(afr[s], bfr, acc[n], 0, 0, 0);
        }
    }

    const size_t prow0 = (size_t)gp0 + w*16 + hi*4;
    #pragma unroll
    for (int n = 0; n < 16; ++n) {          // V cols, bf16
        unsigned short* vp = Vout + prow0*CS + n*16 + l15;
        #pragma unroll
        for (int r = 0; r < 4; ++r)
            vp[(size_t)r*CS] = f2bf(acc[n][r]);
    }
    #pragma unroll
    for (int n = 16; n < 18; ++n) {         // qk cols -> cost = exp(qk)
        float* cp = costO + prow0*32 + (n-16)*16 + l15;
        #pragma unroll
        for (int r = 0; r < 4; ++r)
            cp[(size_t)r*32] = __expf(acc[n][r]);
    }
}

// ---------- kernel 2: 9-tap aggregation, 1 wave = 1 output pixel ----------
// No LDS, no barriers. All lanes compute the 32 qh costs (qh = lane&31,
// duplicated in both halves), reduce over q via shfl_xor(8,16), broadcast
// coef[k][h] via shfl(src = lane>>3). V loads ushort4 (512B/wave/tap).
__global__ __launch_bounds__(256) void k2_agg(
    const float* __restrict__ cost, const unsigned short* __restrict__ V,
    const float* __restrict__ ascale, const float* __restrict__ rpb,
    unsigned short* __restrict__ pre)
{
    const int t    = threadIdx.x;
    const int lane = t & 63;
    const int w    = t >> 6;
    const int gp   = blockIdx.x*4 + w;    // global out-pixel = b*784 + ho*28 + wo
    const int b    = gp / NOPIX;
    const int rem  = gp % NOPIX;
    const int ho   = rem / WOUT, wo = rem % WOUT;
    const int qh   = lane & 31;

    int pk[9];
    #pragma unroll
    for (int k = 0; k < 9; ++k) {
        const int y  = 2*ho - 1 + k/3;
        const int xx = 2*wo - 1 + k%3;
        const bool v = ((unsigned)y < (unsigned)HIMG) && ((unsigned)xx < (unsigned)WIMG);
        pk[k] = v ? (y*WIMG + xx) : -1;
    }

    // per-qh: den and cp[k]
    float cp[9];
    float den = 0.f;
    #pragma unroll
    for (int k = 0; k < 9; ++k) {
        const float s  = (pk[k] >= 0) ? cost[((size_t)(b*NPIX) + pk[k])*32 + qh] : 0.f;
        const float wd = __expf(rpb[k*32 + qh]);
        den   = fmaf(wd, s, den);
        cp[k] = wd * ascale[k*32 + qh] * s;
    }
    const float rden = 1.f / den;

    // coef[k][h] = sum_q cp[k][q*8+h]/den ; then broadcast to lane's h = lane>>3
    float coef[9];
    #pragma unroll
    for (int k = 0; k < 9; ++k) {
        float v = cp[k] * rden;
        v += __shfl_xor(v, 8);
        v += __shfl_xor(v, 16);
        coef[k] = __shfl(v, lane >> 3);    // lane s holds h == s for s < 8
    }

    // accumulate 4 channels (lane*4 .. +3)
    float a0 = 0.f, a1 = 0.f, a2 = 0.f, a3 = 0.f;
    #pragma unroll
    for (int k = 0; k < 9; ++k) {
        const int p = (pk[k] >= 0) ? pk[k] : 0;       // coef==0 for invalid taps
        const ushort4 v4 = *(const ushort4*)(V + ((size_t)(b*NPIX) + p)*CS + lane*4);
        a0 = fmaf(coef[k], bf2f(v4.x), a0);
        a1 = fmaf(coef[k], bf2f(v4.y), a1);
        a2 = fmaf(coef[k], bf2f(v4.z), a2);
        a3 = fmaf(coef[k], bf2f(v4.w), a3);
    }
    ushort4 o;
    o.x = f2bf(a0); o.y = f2bf(a1); o.z = f2bf(a2); o.w = f2bf(a3);
    *(ushort4*)(pre + (size_t)gp*CS + lane*4) = o;
}

// ---------- kernel 3: out = Wout @ pre^T via MFMA, hi/lo split A ----------
__global__ __launch_bounds__(256) void k3_mfma(
    const unsigned short* __restrict__ pre, const unsigned short* __restrict__ WHi,
    const unsigned short* __restrict__ WLo, float* __restrict__ out)
{
    const int t    = threadIdx.x;
    const int lane = t & 63;
    const int w    = t >> 6;
    const int l15  = lane & 15;
    const int hi   = lane >> 4;
    const int blk  = blockIdx.x;           // b*28 + otile*7 + ptile
    const int b    = blk / 28;
    const int rem  = blk % 28;
    const int o0   = (rem / 7) * 64 + w * 16;
    const int p0   = (rem % 7) * 112;

    bf16x8 aH[8], aL[8];
    {
        const unsigned short* ah = WHi + (size_t)(o0 + l15)*CS + hi*8;
        const unsigned short* al = WLo + (size_t)(o0 + l15)*CS + hi*8;
        #pragma unroll
        for (int s = 0; s < 8; ++s) {
            aH[s] = *(const bf16x8*)(ah + s*32);
            aL[s] = *(const bf16x8*)(al + s*32);
        }
    }

    const unsigned short* bbase = pre + ((size_t)(b*NOPIX) + p0 + l15)*CS + hi*8;

    f32x4 acc[7];
    #pragma unroll
    for (int n = 0; n < 7; ++n) acc[n] = (f32x4){0.f,0.f,0.f,0.f};

    #pragma unroll
    for (int n = 0; n < 7; ++n) {
        const unsigned short* bn = bbase + (size_t)(n*16)*CS;
        bf16x8 bf[8];
        #pragma unroll
        for (int s = 0; s < 8; ++s) bf[s] = *(const bf16x8*)(bn + s*32);
        #pragma unroll
        for (int s = 0; s < 8; ++s) {
            acc[n] = __builtin_amdgcn_mfma_f32_16x16x32_bf16(aH[s], bf[s], acc[n], 0, 0, 0);
            acc[n] = __builtin_amdgcn_mfma_f32_16x16x32_bf16(aL[s], bf[s], acc[n], 0, 0, 0);
        }
    }

    #pragma unroll
    for (int n = 0; n < 7; ++n) {
        #pragma unroll
        for (int r = 0; r < 4; ++r)
            out[((size_t)(b*CS) + o0 + hi*4 + r)*NOPIX + p0 + n*16 + l15] = acc[n][r];
    }
}

extern "C" void kernel_launch(void* const* d_in, const int* in_sizes, int n_in,
                              void* d_out, int out_size, void* d_ws, size_t ws_size,
                              hipStream_t stream) {
    const float* x      = (const float*)d_in[0];
    const float* Wk     = (const float*)d_in[1];
    const float* Wv     = (const float*)d_in[2];
    const float* Wout   = (const float*)d_in[3];
    const float* qp     = (const float*)d_in[4];
    const float* ascale = (const float*)d_in[5];
    const float* rpb    = (const float*)d_in[6];
    float* out = (float*)d_out;

    // ws layout (bytes):
    //   cost f32 : 6,422,528
    //   V bf16   : 25,690,112
    //   pre bf16 : 6,422,528
    //   WoutHi   : 131,072 | WoutLo: 131,072 | Wp: 73,728   -> ~38.9 MB
    char* ws = (char*)d_ws;
    float*          cost = (float*)(ws);
    unsigned short* V    = (unsigned short*)(ws + 6422528);
    unsigned short* pre  = (unsigned short*)(ws + 32112640);
    unsigned short* WHi  = (unsigned short*)(ws + 38535168);
    unsigned short* WLo  = (unsigned short*)(ws + 38666240);
    unsigned short* Wp   = (unsigned short*)(ws + 38797312);

    kW_prep<<<17, 256, 0, stream>>>(Wout, Wk, Wv, qp, WHi, WLo, Wp);
    k1_mfma<<<(BATCH*NPIX)/64, 256, 0, stream>>>(x, Wp, cost, V);
    k2_agg <<<(BATCH*NOPIX)/4, 256, 0, stream>>>(cost, V, ascale, rpb, pre);
    k3_mfma<<<BATCH*28, 256, 0, stream>>>(pre, WHi, WLo, out);
}